// Round 13
// baseline (1105.901 us; speedup 1.0000x reference)
//
#include <hip/hip_runtime.h>
#include <hip/hip_bf16.h>
#include <hip/hip_fp16.h>

#define SEQ 8192
#define DM  1024   // d_in == d_out == 1024

typedef __attribute__((ext_vector_type(8))) short    bf16x8;
typedef __attribute__((ext_vector_type(8))) _Float16 f16x8;
typedef __attribute__((ext_vector_type(4))) float    f32x4;

union H8 { _Float16 h[8]; int4 v; };

__device__ __forceinline__ unsigned short f2bf(float f) {
    union { float f; unsigned u; } x; x.f = f;
    unsigned r = x.u + 0x7fffu + ((x.u >> 16) & 1u);
    return (unsigned short)(r >> 16);
}
__device__ __forceinline__ float bf2f(unsigned short h) {
    union { unsigned u; float f; } x; x.u = ((unsigned)h) << 16;
    return x.f;
}

// async global->LDS, 16B per lane; lds dest wave-uniform base (HW adds lane*16)
__device__ __forceinline__ void gld16(const unsigned short* g, unsigned short* l) {
    __builtin_amdgcn_global_load_lds(
        (const __attribute__((address_space(1))) void*)g,
        (__attribute__((address_space(3))) void*)l, 16, 0, 0);
}

// ------- prep: [0,8192) split x + row-sums r; [8192,10240) elementwise split Wq/Wk
//         (RAW layout — G-GEMM contracts over n which is contiguous); [10240,10496)
//         transpose+split Wv. -------
__global__ __launch_bounds__(256) void prep_kernel(const float* __restrict__ x,
    unsigned short* __restrict__ xhi, unsigned short* __restrict__ xlo,
    float* __restrict__ rsum,
    const float* W0, const float* W1, const float* W2,
    unsigned short* Wqh, unsigned short* Wql,
    unsigned short* Wkh, unsigned short* Wkl,
    unsigned short* H2, unsigned short* L2)
{
    __shared__ float tile[64][65];
    __shared__ float rbuf[4];
    int t = threadIdx.x;

    if (blockIdx.x < 8192) {
        // ---- split x row (1024 els) + fp32 row sum for the rank-1 term ----
        int base = blockIdx.x * 1024 + t * 4;
        float4 v = *(const float4*)(x + base);
        float f[4] = {v.x, v.y, v.z, v.w};
        unsigned short h[4], l[4];
#pragma unroll
        for (int j = 0; j < 4; j++) { h[j] = f2bf(f[j]); l[j] = f2bf(f[j] - bf2f(h[j])); }
        ushort4 hv = {h[0], h[1], h[2], h[3]};
        ushort4 lv = {l[0], l[1], l[2], l[3]};
        *(ushort4*)(xhi + base) = hv;
        *(ushort4*)(xlo + base) = lv;
        float s4 = f[0] + f[1] + f[2] + f[3];
#pragma unroll
        for (int sh = 1; sh < 64; sh <<= 1) s4 += __shfl_xor(s4, sh);
        if ((t & 63) == 0) rbuf[t >> 6] = s4;
        __syncthreads();
        if (t == 0) rsum[blockIdx.x] = rbuf[0] + rbuf[1] + rbuf[2] + rbuf[3];
        return;
    }

    if (blockIdx.x < 8192 + 2048) {
        // ---- elementwise split Wq / Wk, raw [d][n] layout ----
        int id = blockIdx.x - 8192;            // 0..2047
        const float* W = (id < 1024) ? W0 : W1;
        unsigned short* H = (id < 1024) ? Wqh : Wkh;
        unsigned short* L = (id < 1024) ? Wql : Wkl;
        int base = (id & 1023) * 1024 + t * 4;
        float4 v = *(const float4*)(W + base);
        float f[4] = {v.x, v.y, v.z, v.w};
        unsigned short h[4], l[4];
#pragma unroll
        for (int j = 0; j < 4; j++) { h[j] = f2bf(f[j]); l[j] = f2bf(f[j] - bf2f(h[j])); }
        ushort4 hv = {h[0], h[1], h[2], h[3]};
        ushort4 lv = {l[0], l[1], l[2], l[3]};
        *(ushort4*)(H + base) = hv;
        *(ushort4*)(L + base) = lv;
        return;
    }

    // ---- transpose + split Wv [1024k x 1024n] -> Wvt hi/lo [n][k] ----
    int id2 = blockIdx.x - 10240;        // 0..255
    int bn = (id2 & 15) * 64;
    int bk = (id2 >> 4) * 64;
    const float* W = W2;

#pragma unroll
    for (int p = 0; p < 4; p++) {
        int r = p * 16 + (t >> 4);
        int c = (t & 15) * 4;
        float4 v = *(const float4*)(W + (size_t)(bk + r) * DM + bn + c);
        tile[r][c] = v.x; tile[r][c+1] = v.y; tile[r][c+2] = v.z; tile[r][c+3] = v.w;
    }
    __syncthreads();
#pragma unroll
    for (int p = 0; p < 2; p++) {
        int task = p * 256 + t;
        int rn = task >> 3;
        int kc = (task & 7) * 8;
        union { unsigned short u[8]; int4 v; } hh, ll;
#pragma unroll
        for (int j = 0; j < 8; j++) {
            float f = tile[kc + j][rn];
            hh.u[j] = f2bf(f);
            ll.u[j] = f2bf(f - bf2f(hh.u[j]));
        }
        size_t o = (size_t)(bn + rn) * DM + bk + kc;
        *(int4*)(H2 + o) = hh.v;
        *(int4*)(L2 + o) = ll.v;
    }
}

// ============ 128x128-tile GEMM, 256 thr (4 waves, 64x64 each), BK=32 ============
// R7 (verified): 1-barrier-per-K-tile schedule, 2 blocks/CU, both-sides LDS swizzle.
// MODE 0: split bf16 -> split bf16 out (y = x@G' projection).
// MODE 1: bf16 -> f16 out written TRANSPOSED (V-proj direct to Vt) [R9 verified].
// MODE 3: PV with fused softmax scale from LDS-staged Sc [R6 verified].
// MODE 5: split-K G partial (blockIdx.z covers n-range, NT=4) [R11 verified].
template<int MODE, int KD>
__global__ __launch_bounds__(256, 2) void gemm128(
    const unsigned short* A,   const unsigned short* Alo,
    const unsigned short* B_,  const unsigned short* Blo_,
    unsigned short* Chi, unsigned short* Clo,
    _Float16* Cf16, float* Cf32, const float* __restrict__ Scp)
{
    constexpr bool SPLIT = (MODE == 0 || MODE == 5);
    constexpr int NT = (MODE == 5) ? 4 : KD / 32;
    __shared__ alignas(16) unsigned short sAhi[2][128 * 32];
    __shared__ alignas(16) unsigned short sBhi[2][128 * 32];
    __shared__ alignas(16) unsigned short sAlo[SPLIT ? 2 * 128 * 32 : 16];
    __shared__ alignas(16) unsigned short sBlo[SPLIT ? 2 * 128 * 32 : 16];
    __shared__ alignas(16) _Float16 sSc[(MODE == 3) ? 128 * 130 : 8];

    const unsigned short* B   = B_;
    const unsigned short* Blo = Blo_;

    const int m0 = blockIdx.x * 128;
    const int n0 = blockIdx.y * 128;
    const int kbase = (MODE == 5) ? (int)blockIdx.z * 128 : 0;
    const int t = threadIdx.x;
    const int wave = t >> 6, lane = t & 63;
    const int wr = wave >> 1, wc = wave & 1;    // wave quadrant (64x64)
    const int i16 = lane & 15, quad = lane >> 4;

    // staging: wave stages rows wave*32 .. +31; source col pre-swizzled (rule 21)
    const int rs = wave * 32 + (lane >> 2);
    const int scol = ((lane & 3) ^ ((lane >> 3) & 3)) << 3;
    const size_t aoff = (size_t)(m0 + rs) * KD + scol;
    const size_t boff = (size_t)(n0 + rs) * KD + scol;
    const int ldsb = wave * 1024;   // element offset of this wave's staging region

    // read-side swizzled fragment offsets (loop-invariant)
    int offA[4], offB[4];
#pragma unroll
    for (int mt = 0; mt < 4; mt++) {
        int row = wr * 64 + mt * 16 + i16;
        offA[mt] = row * 32 + ((quad ^ ((row >> 1) & 3)) << 3);
    }
#pragma unroll
    for (int nt = 0; nt < 4; nt++) {
        int row = wc * 64 + nt * 16 + i16;
        offB[nt] = row * 32 + ((quad ^ ((row >> 1) & 3)) << 3);
    }

    // ---- MODE 3: one-time Sc slice -> LDS (f16), coalesced float4 reads ----
    if constexpr (MODE == 3) {
#pragma unroll
        for (int i = 0; i < 16; i++) {
            int idx = i * 1024 + t * 4;          // element index, multiple of 4
            int row = idx >> 7, col = idx & 127;
            float4 v = *(const float4*)(Scp + (size_t)(m0 + row) * 128 + col);
            _Float16* d = sSc + row * 130 + col;
            d[0] = (_Float16)v.x; d[1] = (_Float16)v.y;
            d[2] = (_Float16)v.z; d[3] = (_Float16)v.w;
        }
    }

    auto STAGE = [&](int buf, int k) {
        gld16(A + aoff + k,           sAhi[buf] + ldsb);
        gld16(A + aoff + 16 * KD + k, sAhi[buf] + ldsb + 512);
        gld16(B + boff + k,           sBhi[buf] + ldsb);
        gld16(B + boff + 16 * KD + k, sBhi[buf] + ldsb + 512);
        if constexpr (SPLIT) {
            gld16(Alo + aoff + k,           sAlo + buf * 4096 + ldsb);
            gld16(Alo + aoff + 16 * KD + k, sAlo + buf * 4096 + ldsb + 512);
            gld16(Blo + boff + k,           sBlo + buf * 4096 + ldsb);
            gld16(Blo + boff + 16 * KD + k, sBlo + buf * 4096 + ldsb + 512);
        }
    };

    f32x4 acc[4][4] = {};

    // prologue: stage tile 0; __syncthreads drains vmcnt (staging) AND lgkm (Sc writes)
    STAGE(0, kbase);
    __syncthreads();

    for (int kt = 0; kt < NT; ++kt) {
        const int cur = kt & 1;
        const int k = kbase + kt * 32;

        // ---- fragment reads from buf cur ----
        bf16x8 ahi[4], alo[4], bhi[4], blo[4];
#pragma unroll
        for (int mt = 0; mt < 4; mt++) {
            ahi[mt] = *(const bf16x8*)(sAhi[cur] + offA[mt]);
            if constexpr (SPLIT) alo[mt] = *(const bf16x8*)(sAlo + cur * 4096 + offA[mt]);
        }
#pragma unroll
        for (int nt = 0; nt < 4; nt++) {
            bhi[nt] = *(const bf16x8*)(sBhi[cur] + offB[nt]);
            if constexpr (SPLIT) blo[nt] = *(const bf16x8*)(sBlo + cur * 4096 + offB[nt]);
        }
        if constexpr (MODE == 3) {
#pragma unroll
            for (int mt = 0; mt < 4; mt++) {
                _Float16 sc = sSc[(wr * 64 + mt * 16 + i16) * 130 + (k >> 6)];
                f16x8 av = __builtin_bit_cast(f16x8, ahi[mt]);
                av = av * sc;
                ahi[mt] = __builtin_bit_cast(bf16x8, av);
            }
        }

        // ---- issue next tile's staging (drained at tile end) ----
        if (kt + 1 < NT) STAGE(cur ^ 1, k + 32);

        // ---- MFMA ----
        __builtin_amdgcn_s_setprio(1);
#pragma unroll
        for (int nt = 0; nt < 4; nt++)
#pragma unroll
            for (int mt = 0; mt < 4; mt++) {
                if constexpr (MODE == 3) {
                    acc[mt][nt] = __builtin_amdgcn_mfma_f32_16x16x32_f16(
                        __builtin_bit_cast(f16x8, ahi[mt]), __builtin_bit_cast(f16x8, bhi[nt]),
                        acc[mt][nt], 0, 0, 0);
                } else {
                    acc[mt][nt] = __builtin_amdgcn_mfma_f32_16x16x32_bf16(ahi[mt], bhi[nt], acc[mt][nt], 0, 0, 0);
                    if constexpr (SPLIT) {
                        acc[mt][nt] = __builtin_amdgcn_mfma_f32_16x16x32_bf16(ahi[mt], blo[nt], acc[mt][nt], 0, 0, 0);
                        acc[mt][nt] = __builtin_amdgcn_mfma_f32_16x16x32_bf16(alo[mt], bhi[nt], acc[mt][nt], 0, 0, 0);
                    }
                }
            }
        __builtin_amdgcn_s_setprio(0);

        // ---- tile-end: drain next-tile staging, single barrier ----
        asm volatile("s_waitcnt vmcnt(0)" ::: "memory");
        __builtin_amdgcn_s_barrier();
        __builtin_amdgcn_sched_barrier(0);
    }

    // ---------------- epilogues ----------------
    if constexpr (MODE == 0) {
#pragma unroll
        for (int mt = 0; mt < 4; mt++)
#pragma unroll
            for (int nt = 0; nt < 4; nt++)
#pragma unroll
                for (int r = 0; r < 4; r++) {
                    int row = m0 + wr * 64 + mt * 16 + quad * 4 + r;
                    int col = n0 + wc * 64 + nt * 16 + i16;
                    float v = acc[mt][nt][r];
                    unsigned short h = f2bf(v);
                    Chi[(size_t)row * DM + col] = h;
                    Clo[(size_t)row * DM + col] = f2bf(v - bf2f(h));
                }
    } else if constexpr (MODE == 1) {
        // transposed write: Vt[col][row], 4 consecutive rows per lane -> one 8B store
#pragma unroll
        for (int mt = 0; mt < 4; mt++)
#pragma unroll
            for (int nt = 0; nt < 4; nt++) {
                int row0 = m0 + wr * 64 + mt * 16 + quad * 4;
                int col  = n0 + wc * 64 + nt * 16 + i16;
                union { _Float16 h[4]; unsigned long long q; } p;
#pragma unroll
                for (int r = 0; r < 4; r++) p.h[r] = (_Float16)acc[mt][nt][r];
                *(unsigned long long*)(Cf16 + (size_t)col * SEQ + row0) = p.q;
            }
    } else if constexpr (MODE == 5) {
        // fp32 partial, transposed: Gp[z][e][d], one float4 store per fragment
        float* Gp = Cf32 + ((size_t)blockIdx.z << 20);
#pragma unroll
        for (int mt = 0; mt < 4; mt++)
#pragma unroll
            for (int nt = 0; nt < 4; nt++) {
                int row0 = m0 + wr * 64 + mt * 16 + quad * 4;
                int col  = n0 + wc * 64 + nt * 16 + i16;
                union { float f[4]; float4 v; } p;
#pragma unroll
                for (int r = 0; r < 4; r++) p.f[r] = acc[mt][nt][r];
                *(float4*)(Gp + (size_t)col * DM + row0) = p.v;
            }
    } else {  // MODE 3: PV, f32 out
#pragma unroll
        for (int mt = 0; mt < 4; mt++)
#pragma unroll
            for (int nt = 0; nt < 4; nt++)
#pragma unroll
                for (int r = 0; r < 4; r++) {
                    int row = m0 + wr * 64 + mt * 16 + quad * 4 + r;
                    int col = n0 + wc * 64 + nt * 16 + i16;
                    Cf32[(size_t)row * DM + col] = acc[mt][nt][r];
                }
    }
}

// ------- greduce: Ght[e][d] = split(sum_z Gp[z][e][d] - 256), coalesced -------
__global__ __launch_bounds__(256) void greduce(const float* __restrict__ Gp,
    unsigned short* __restrict__ Ghi, unsigned short* __restrict__ Glo)
{
    int e = blockIdx.x;
    int d0 = threadIdx.x * 4;
    float s[4] = {0.f, 0.f, 0.f, 0.f};
#pragma unroll
    for (int z = 0; z < 8; z++) {
        float4 v = *(const float4*)(Gp + ((size_t)z << 20) + (size_t)e * DM + d0);
        s[0] += v.x; s[1] += v.y; s[2] += v.z; s[3] += v.w;
    }
    unsigned short h[4], l[4];
#pragma unroll
    for (int j = 0; j < 4; j++) {
        float f = s[j] - 256.0f;
        h[j] = f2bf(f);
        l[j] = f2bf(f - bf2f(h[j]));
    }
    ushort4 hv = {h[0], h[1], h[2], h[3]};
    ushort4 lv = {l[0], l[1], l[2], l[3]};
    *(ushort4*)(Ghi + (size_t)e * DM + d0) = hv;
    *(ushort4*)(Glo + (size_t)e * DM + d0) = lv;
}

// ============ scores: 256x256 tile, 1024 thr (16 waves 4Mx4N of 64x64), BK=32 ============
// R12 structure (best-known). R13: template<int V> ABLATION variants (rule 17 keep-alive):
//   V=0 real; V=1 NOMFMA (reads+stage+barriers); V=2 NOREADS (stage+MFMA+barriers,
//   synthetic loop-invariant fragments); V=3 NOSTAGE (reads+MFMA+barriers, stale LDS).
// Variants are dispatched AFTER the real pipeline finishes (outputs dead-clobbered).
// G-trick epilogue: s = acc*scale + 8*rM*rN (exact rank-1 from fp32 row sums).
template<int V>
__global__ __launch_bounds__(1024) void scores256(
    const unsigned short* __restrict__ Yh, const unsigned short* __restrict__ Yl,
    const unsigned short* __restrict__ Xh, const unsigned short* __restrict__ Xl,
    const float* __restrict__ rsum,
    _Float16* __restrict__ Eo, float* __restrict__ Tt, float* __restrict__ Zt)
{
    constexpr int KD = 1024;
    constexpr int NT = KD / 32;                       // 32 K-tiles
    // layout: buf(0/1) x {Yh,Yl,Xh,Xl} x [256][32]  = 128 KiB
    __shared__ alignas(16) unsigned short lds[2 * 4 * 8192];
    __shared__ float srM[256], srN[256];

    // bijective XCD swizzle (nwg=1024 % 8 == 0); m-major within an XCD
    const int flat = blockIdx.y * gridDim.x + blockIdx.x;
    const int wg = (flat & 7) * 128 + (flat >> 3);
    const int m0 = (wg >> 5) << 8;
    const int n0 = (wg & 31) << 8;

    const int t = threadIdx.x;
    const int wave = t >> 6, lane = t & 63;
    const int wr = wave >> 2, wc = wave & 3;          // 4x4 waves, 64x64 each
    const int i16 = lane & 15, quad = lane >> 4;

    // rank-1 row-sum slices -> LDS (visible by the prologue barrier)
    if (t < 256) srM[t] = rsum[m0 + t];
    else if (t < 512) srN[t - 256] = rsum[n0 + t - 256];

    // staging: 1024 lanes x 16B = one 256x32 stream per gld16 call
    const int srow = wave * 16 + (lane >> 2);
    const int scol = ((lane & 3) ^ ((lane >> 3) & 3)) << 3;
    const size_t ga = (size_t)(m0 + srow) * KD + scol;
    const size_t gb = (size_t)(n0 + srow) * KD + scol;
    const int ldw = wave * 512;                        // wave-uniform LDS el offset

    // fragment LDS element offsets (loop-invariant, swizzled)
    int offA[4], offB[4];
#pragma unroll
    for (int mt = 0; mt < 4; mt++) {
        int row = wr * 64 + mt * 16 + i16;
        offA[mt] = row * 32 + ((quad ^ ((row >> 1) & 3)) << 3);
    }
#pragma unroll
    for (int nt = 0; nt < 4; nt++) {
        int row = wc * 64 + nt * 16 + i16;
        offB[nt] = row * 32 + ((quad ^ ((row >> 1) & 3)) << 3);
    }

    f32x4 acc[4][4] = {};

    // V2: synthetic loop-invariant fragments (cheap, register-only; MFMA chain through
    // acc keeps them live — no DCE, no LDS dependence)
    bf16x8 synA[4], synB[4];
    if constexpr (V == 2) {
#pragma unroll
        for (int i = 0; i < 4; i++) {
            f32x4 sa = {(float)(t + i), (float)(t + i + 1), (float)(t + i + 2), (float)(t + i + 3)};
            f32x4 sb = {(float)(t - i), (float)(t - i - 1), (float)(t - i - 2), (float)(t - i - 3)};
            synA[i] = __builtin_bit_cast(bf16x8, sa);
            synB[i] = __builtin_bit_cast(bf16x8, sb);
        }
    }

    auto STAGE = [&](int buf, int kt) {
        unsigned short* p = lds + buf * 32768;
        const int k = kt * 32;
        gld16(Yh + ga + k, p + ldw);
        gld16(Yl + ga + k, p + 8192  + ldw);
        gld16(Xh + gb + k, p + 16384 + ldw);
        gld16(Xl + gb + k, p + 24576 + ldw);
    };

    // ---- prologue ----
    if constexpr (V != 3) {
        STAGE(0, 0);
        asm volatile("s_waitcnt vmcnt(0)" ::: "memory");
    }
    __builtin_amdgcn_s_barrier();
    __builtin_amdgcn_sched_barrier(0);

    for (int kt = 0; kt < NT; ++kt) {
        const int cur = kt & 1;
        const unsigned short* pAh = lds + cur * 32768;
        const unsigned short* pAl = pAh + 8192;
        const unsigned short* pBh = pAh + 16384;
        const unsigned short* pBl = pAh + 24576;

        // ---- B fragments (8 reads, held); A streamed per row inside MFMA loop ----
        bf16x8 bh[4], bl[4];
        if constexpr (V != 2) {
#pragma unroll
            for (int ni = 0; ni < 4; ni++) {
                bh[ni] = *(const bf16x8*)(pBh + offB[ni]);
                bl[ni] = *(const bf16x8*)(pBl + offB[ni]);
            }
        } else {
#pragma unroll
            for (int ni = 0; ni < 4; ni++) { bh[ni] = synB[ni]; bl[ni] = synA[ni]; }
        }
        // ---- issue next tile's staging (drained at tile end) ----
        if constexpr (V != 3) { if (kt + 1 < NT) STAGE(cur ^ 1, kt + 1); }

        __builtin_amdgcn_s_setprio(1);
#pragma unroll
        for (int mi = 0; mi < 4; mi++) {
            bf16x8 ah, al;
            if constexpr (V != 2) {
                ah = *(const bf16x8*)(pAh + offA[mi]);
                al = *(const bf16x8*)(pAl + offA[mi]);
            } else { ah = synA[mi]; al = synB[mi]; }
            if constexpr (V == 1) {
                // keep reads live without MFMA (rule 17)
                asm volatile("" :: "v"(__builtin_bit_cast(f32x4, ah)),
                                   "v"(__builtin_bit_cast(f32x4, al)),
                                   "v"(__builtin_bit_cast(f32x4, bh[mi])),
                                   "v"(__builtin_bit_cast(f32x4, bl[mi])));
            } else {
#pragma unroll
                for (int ni = 0; ni < 4; ni++) {
                    f32x4 c = acc[mi][ni];
                    c = __builtin_amdgcn_mfma_f32_16x16x32_bf16(ah, bh[ni], c, 0, 0, 0);
                    c = __builtin_amdgcn_mfma_f32_16x16x32_bf16(ah, bl[ni], c, 0, 0, 0);
                    c = __builtin_amdgcn_mfma_f32_16x16x32_bf16(al, bh[ni], c, 0, 0, 0);
                    acc[mi][ni] = c;
                }
            }
        }
        __builtin_amdgcn_s_setprio(0);

        // ---- tile-end: drain next-tile staging, single barrier ----
        if constexpr (V != 3) asm volatile("s_waitcnt vmcnt(0)" ::: "memory");
        __builtin_amdgcn_s_barrier();
        __builtin_amdgcn_sched_barrier(0);
    }

    // ---- epilogue: s = acc*scale + 8*rM*rN; E = exp(s - tile64max), Tt, Zt ----
    const float scale = 0.03125f;  // 1/sqrt(1024)
    const float RC = 8.0f;         // 256 * scale
    const int tix = (n0 + wc * 64) >> 6;
    const float rn0 = RC * srN[wc * 64 + i16];
    const float rn1 = RC * srN[wc * 64 + 16 + i16];
    const float rn2 = RC * srN[wc * 64 + 32 + i16];
    const float rn3 = RC * srN[wc * 64 + 48 + i16];
#pragma unroll
    for (int mt = 0; mt < 4; mt++)
#pragma unroll
        for (int r = 0; r < 4; r++) {
            float rm = srM[wr * 64 + mt * 16 + quad * 4 + r];
            float s0 = acc[mt][0][r] * scale + rm * rn0;
            float s1 = acc[mt][1][r] * scale + rm * rn1;
            float s2 = acc[mt][2][r] * scale + rm * rn2;
            float s3 = acc[mt][3][r] * scale + rm * rn3;
            float mx = fmaxf(fmaxf(s0, s1), fmaxf(s2, s3));
            mx = fmaxf(mx, __shfl_xor(mx, 1));
            mx = fmaxf(mx, __shfl_xor(mx, 2));
            mx = fmaxf(mx, __shfl_xor(mx, 4));
            mx = fmaxf(mx, __shfl_xor(mx, 8));
            float e0 = __expf(s0 - mx), e1 = __expf(s1 - mx);
            float e2 = __expf(s2 - mx), e3 = __expf(s3 - mx);
            float z = e0 + e1 + e2 + e3;
            z += __shfl_xor(z, 1);
            z += __shfl_xor(z, 2);
            z += __shfl_xor(z, 4);
            z += __shfl_xor(z, 8);
            int row = m0 + wr * 64 + mt * 16 + quad * 4 + r;
            if (i16 == 0) {
                Tt[(size_t)row * 128 + tix] = mx;
                Zt[(size_t)row * 128 + tix] = z;
            }
            size_t eb = (size_t)row * SEQ + n0 + wc * 64 + i16;
            Eo[eb +  0] = (_Float16)e0;
            Eo[eb + 16] = (_Float16)e1;
            Eo[eb + 32] = (_Float16)e2;
            Eo[eb + 48] = (_Float16)e3;
        }
}

// ------- per-row softmax scale from per-tile stats: Sc[r][t] = e^{T-m}/l -------
__global__ __launch_bounds__(256) void sc_reduce(const float* __restrict__ Tt,
    const float* __restrict__ Zt, float* __restrict__ Sc)
{
    int row = blockIdx.x * 4 + (threadIdx.x >> 6);
    int lane = threadIdx.x & 63;
    size_t b = (size_t)row * 128 + lane;
    float t0 = Tt[b], t1 = Tt[b + 64];
    float z0 = Zt[b], z1 = Zt[b + 64];
    float m = fmaxf(t0, t1);
    for (int sh = 1; sh < 64; sh <<= 1) m = fmaxf(m, __shfl_xor(m, sh));
    float l = z0 * __expf(t0 - m) + z1 * __expf(t1 - m);
    for (int sh = 1; sh < 64; sh <<= 1) l += __shfl_xor(l, sh);
    float inv = 1.0f / l;
    Sc[b]      = __expf(t0 - m) * inv;
    Sc[b + 64] = __expf(t1 - m) * inv;
}

extern "C" void kernel_launch(void* const* d_in, const int* in_sizes, int n_in,
                              void* d_out, int out_size, void* d_ws, size_t ws_size,
                              hipStream_t stream)
{
    const float* x  = (const float*)d_in[0];
    const float* Wq = (const float*)d_in[1];
    const float* Wk = (const float*)d_in[2];
    const float* Wv = (const float*)d_in[3];
    float* Out = (float*)d_out;
    char* ws = (char*)d_ws;

    const size_t MB = 1024 * 1024;
    // Region [0,128MB): W splits + G buffers (all dead before scores) then E overwrites.
    unsigned short* Wqh  = (unsigned short*)(ws + 0 * MB);
    unsigned short* Wql  = (unsigned short*)(ws + 2 * MB);
    unsigned short* Wkh  = (unsigned short*)(ws + 4 * MB);
    unsigned short* Wkl  = (unsigned short*)(ws + 6 * MB);
    unsigned short* Wvth = (unsigned short*)(ws + 8 * MB);
    unsigned short* Wvtl = (unsigned short*)(ws + 10 * MB);
    unsigned short* Ghi  = (unsigned short*)(ws + 12 * MB);  // G't [e][d] split
    unsigned short* Glo  = (unsigned short*)(ws + 14 * MB);
    float*          Gp   = (float*)        (ws + 16 * MB);   // 8 x 4MB fp32 partials
    _Float16*       E    = (_Float16*)     (ws + 0 * MB);    // 128 MB

    size_t off = 128 * MB;
    unsigned short* Yhi = (unsigned short*)(ws + off); off += 16 * MB;
    unsigned short* Ylo = (unsigned short*)(ws + off); off += 16 * MB;
    unsigned short* xhi = (unsigned short*)(ws + off); off += 16 * MB;  // live thru scores
    unsigned short* xlo = (unsigned short*)(ws + off); off += 16 * MB;
    _Float16*       Vt  = (_Float16*)      (ws + off); off += 16 * MB;
    float*          Tt  = (float*)         (ws + off); off += (size_t)SEQ * 128 * 4;
    float*          Zt  = (float*)         (ws + off); off += (size_t)SEQ * 128 * 4;
    float*          Sc  = (float*)         (ws + off); off += (size_t)SEQ * 128 * 4;
    float*          rs  = (float*)         (ws + off); off += (size_t)SEQ * 4;

    // 1. split x (+row sums), elementwise-split Wq/Wk, transpose+split Wv
    prep_kernel<<<8192 + 2048 + 256, 256, 0, stream>>>(x, xhi, xlo, rs, Wq, Wk, Wv,
        Wqh, Wql, Wkh, Wkl, Wvth, Wvtl);
    // 2. G partials: split-K x8 (512 blocks, 4 K-tiles deep each)
    gemm128<5, DM><<<dim3(8, 8, 8), 256, 0, stream>>>(
        Wqh, Wql, Wkh, Wkl, nullptr, nullptr, nullptr, Gp, nullptr);
    // 2b. reduce partials -> G' = sum - 256, transposed split Ght[e][d]
    greduce<<<1024, 256, 0, stream>>>(Gp, Ghi, Glo);
    // 3. V projection, output written TRANSPOSED directly to Vt
    gemm128<1, DM><<<dim3(SEQ / 128, DM / 128), 256, 0, stream>>>(
        xhi, nullptr, Wvth, nullptr, nullptr, nullptr, (_Float16*)Vt, nullptr, nullptr);
    // 4. y' = x @ G' (split out) — replaces BOTH Q and K projections
    gemm128<0, DM><<<dim3(SEQ / 128, DM / 128), 256, 0, stream>>>(
        xhi, xlo, Ghi, Glo, Yhi, Ylo, nullptr, nullptr, nullptr);
    // 5. scores: S = y' x^T * scale + 8 r r^T -> E, Tt, Zt   [V0 = real]
    scores256<0><<<dim3(SEQ / 256, SEQ / 256), 1024, 0, stream>>>(
        Yhi, Ylo, xhi, xlo, rs, E, Tt, Zt);
    // 6. per-row/tile softmax scale
    sc_reduce<<<SEQ / 4, 256, 0, stream>>>(Tt, Zt, Sc);
    // 7. O = P @ V with P = E*Sc fused via LDS-staged Sc
    gemm128<3, SEQ><<<dim3(SEQ / 128, DM / 128), 256, 0, stream>>>(
        (const unsigned short*)E, nullptr, (const unsigned short*)Vt, nullptr,
        nullptr, nullptr, nullptr, Out, Sc);

    // ---- R13 ABLATION (Out already written; E/Tt/Zt dead — safe to clobber).
    // Half grid (512 blocks) to bound the dur_us cost; interpret durations x2.
    // V1 = NOMFMA (reads+stage+bar), V2 = NOREADS (stage+MFMA+bar), V3 = NOSTAGE.
    scores256<1><<<dim3(32, 16), 1024, 0, stream>>>(Yhi, Ylo, xhi, xlo, rs, E, Tt, Zt);
    scores256<2><<<dim3(32, 16), 1024, 0, stream>>>(Yhi, Ylo, xhi, xlo, rs, E, Tt, Zt);
    scores256<3><<<dim3(32, 16), 1024, 0, stream>>>(Yhi, Ylo, xhi, xlo, rs, E, Tt, Zt);
}

// Round 14
// 632.199 us; speedup vs baseline: 1.7493x; 1.7493x over previous
//
#include <hip/hip_runtime.h>
#include <hip/hip_bf16.h>
#include <hip/hip_fp16.h>

#define SEQ 8192
#define DM  1024   // d_in == d_out == 1024

typedef __attribute__((ext_vector_type(8))) short    bf16x8;
typedef __attribute__((ext_vector_type(8))) _Float16 f16x8;
typedef __attribute__((ext_vector_type(4))) float    f32x4;

union H8 { _Float16 h[8]; int4 v; };

__device__ __forceinline__ unsigned short f2bf(float f) {
    union { float f; unsigned u; } x; x.f = f;
    unsigned r = x.u + 0x7fffu + ((x.u >> 16) & 1u);
    return (unsigned short)(r >> 16);
}
__device__ __forceinline__ float bf2f(unsigned short h) {
    union { unsigned u; float f; } x; x.u = ((unsigned)h) << 16;
    return x.f;
}

// async global->LDS, 16B per lane; lds dest wave-uniform base (HW adds lane*16)
__device__ __forceinline__ void gld16(const unsigned short* g, unsigned short* l) {
    __builtin_amdgcn_global_load_lds(
        (const __attribute__((address_space(1))) void*)g,
        (__attribute__((address_space(3))) void*)l, 16, 0, 0);
}

// ------- prep: [0,8192) split x (bf16 hi/lo for y-proj, f16 single for scores B)
//         + row-sums r; [8192,10240) elementwise split Wq/Wk (RAW layout);
//         [10240,10496) transpose+split Wv. -------
__global__ __launch_bounds__(256) void prep_kernel(const float* __restrict__ x,
    unsigned short* __restrict__ xhi, unsigned short* __restrict__ xlo,
    _Float16* __restrict__ xf,
    float* __restrict__ rsum,
    const float* W0, const float* W1, const float* W2,
    unsigned short* Wqh, unsigned short* Wql,
    unsigned short* Wkh, unsigned short* Wkl,
    unsigned short* H2, unsigned short* L2)
{
    __shared__ float tile[64][65];
    __shared__ float rbuf[4];
    int t = threadIdx.x;

    if (blockIdx.x < 8192) {
        // ---- split x row: bf16 hi/lo + f16 single + fp32 row sum ----
        int base = blockIdx.x * 1024 + t * 4;
        float4 v = *(const float4*)(x + base);
        float f[4] = {v.x, v.y, v.z, v.w};
        unsigned short h[4], l[4];
        union { _Float16 h4[4]; unsigned long long q; } xq;
#pragma unroll
        for (int j = 0; j < 4; j++) {
            h[j] = f2bf(f[j]); l[j] = f2bf(f[j] - bf2f(h[j]));
            xq.h4[j] = (_Float16)f[j];
        }
        ushort4 hv = {h[0], h[1], h[2], h[3]};
        ushort4 lv = {l[0], l[1], l[2], l[3]};
        *(ushort4*)(xhi + base) = hv;
        *(ushort4*)(xlo + base) = lv;
        *(unsigned long long*)(xf + base) = xq.q;
        float s4 = f[0] + f[1] + f[2] + f[3];
#pragma unroll
        for (int sh = 1; sh < 64; sh <<= 1) s4 += __shfl_xor(s4, sh);
        if ((t & 63) == 0) rbuf[t >> 6] = s4;
        __syncthreads();
        if (t == 0) rsum[blockIdx.x] = rbuf[0] + rbuf[1] + rbuf[2] + rbuf[3];
        return;
    }

    if (blockIdx.x < 8192 + 2048) {
        // ---- elementwise split Wq / Wk, raw [d][n] layout ----
        int id = blockIdx.x - 8192;            // 0..2047
        const float* W = (id < 1024) ? W0 : W1;
        unsigned short* H = (id < 1024) ? Wqh : Wkh;
        unsigned short* L = (id < 1024) ? Wql : Wkl;
        int base = (id & 1023) * 1024 + t * 4;
        float4 v = *(const float4*)(W + base);
        float f[4] = {v.x, v.y, v.z, v.w};
        unsigned short h[4], l[4];
#pragma unroll
        for (int j = 0; j < 4; j++) { h[j] = f2bf(f[j]); l[j] = f2bf(f[j] - bf2f(h[j])); }
        ushort4 hv = {h[0], h[1], h[2], h[3]};
        ushort4 lv = {l[0], l[1], l[2], l[3]};
        *(ushort4*)(H + base) = hv;
        *(ushort4*)(L + base) = lv;
        return;
    }

    // ---- transpose + split Wv [1024k x 1024n] -> Wvt hi/lo [n][k] ----
    int id2 = blockIdx.x - 10240;        // 0..255
    int bn = (id2 & 15) * 64;
    int bk = (id2 >> 4) * 64;
    const float* W = W2;

#pragma unroll
    for (int p = 0; p < 4; p++) {
        int r = p * 16 + (t >> 4);
        int c = (t & 15) * 4;
        float4 v = *(const float4*)(W + (size_t)(bk + r) * DM + bn + c);
        tile[r][c] = v.x; tile[r][c+1] = v.y; tile[r][c+2] = v.z; tile[r][c+3] = v.w;
    }
    __syncthreads();
#pragma unroll
    for (int p = 0; p < 2; p++) {
        int task = p * 256 + t;
        int rn = task >> 3;
        int kc = (task & 7) * 8;
        union { unsigned short u[8]; int4 v; } hh, ll;
#pragma unroll
        for (int j = 0; j < 8; j++) {
            float f = tile[kc + j][rn];
            hh.u[j] = f2bf(f);
            ll.u[j] = f2bf(f - bf2f(hh.u[j]));
        }
        size_t o = (size_t)(bn + rn) * DM + bk + kc;
        *(int4*)(H2 + o) = hh.v;
        *(int4*)(L2 + o) = ll.v;
    }
}

// ============ 128x128-tile GEMM, 256 thr (4 waves, 64x64 each), BK=32 ============
// R7 (verified): 1-barrier-per-K-tile schedule, 2 blocks/CU, both-sides LDS swizzle.
// MODE 0: split bf16 inputs -> output written as F16 HI/LO PAIR (R14: feeds the
//         2-MFMA scores; yh=(f16)v, yl=(f16)(v-yh) -> combined 2^-22 rel).
// MODE 1: bf16 -> f16 out written TRANSPOSED (V-proj direct to Vt) [R9 verified].
// MODE 3: PV with fused softmax scale from LDS-staged Sc [R6 verified].
// MODE 5: split-K G partial (blockIdx.z covers n-range, NT=4) [R11 verified].
template<int MODE, int KD>
__global__ __launch_bounds__(256, 2) void gemm128(
    const unsigned short* A,   const unsigned short* Alo,
    const unsigned short* B_,  const unsigned short* Blo_,
    unsigned short* Chi, unsigned short* Clo,
    _Float16* Cf16, float* Cf32, const float* __restrict__ Scp)
{
    constexpr bool SPLIT = (MODE == 0 || MODE == 5);
    constexpr int NT = (MODE == 5) ? 4 : KD / 32;
    __shared__ alignas(16) unsigned short sAhi[2][128 * 32];
    __shared__ alignas(16) unsigned short sBhi[2][128 * 32];
    __shared__ alignas(16) unsigned short sAlo[SPLIT ? 2 * 128 * 32 : 16];
    __shared__ alignas(16) unsigned short sBlo[SPLIT ? 2 * 128 * 32 : 16];
    __shared__ alignas(16) _Float16 sSc[(MODE == 3) ? 128 * 130 : 8];

    const unsigned short* B   = B_;
    const unsigned short* Blo = Blo_;

    const int m0 = blockIdx.x * 128;
    const int n0 = blockIdx.y * 128;
    const int kbase = (MODE == 5) ? (int)blockIdx.z * 128 : 0;
    const int t = threadIdx.x;
    const int wave = t >> 6, lane = t & 63;
    const int wr = wave >> 1, wc = wave & 1;    // wave quadrant (64x64)
    const int i16 = lane & 15, quad = lane >> 4;

    // staging: wave stages rows wave*32 .. +31; source col pre-swizzled (rule 21)
    const int rs = wave * 32 + (lane >> 2);
    const int scol = ((lane & 3) ^ ((lane >> 3) & 3)) << 3;
    const size_t aoff = (size_t)(m0 + rs) * KD + scol;
    const size_t boff = (size_t)(n0 + rs) * KD + scol;
    const int ldsb = wave * 1024;   // element offset of this wave's staging region

    // read-side swizzled fragment offsets (loop-invariant)
    int offA[4], offB[4];
#pragma unroll
    for (int mt = 0; mt < 4; mt++) {
        int row = wr * 64 + mt * 16 + i16;
        offA[mt] = row * 32 + ((quad ^ ((row >> 1) & 3)) << 3);
    }
#pragma unroll
    for (int nt = 0; nt < 4; nt++) {
        int row = wc * 64 + nt * 16 + i16;
        offB[nt] = row * 32 + ((quad ^ ((row >> 1) & 3)) << 3);
    }

    // ---- MODE 3: one-time Sc slice -> LDS (f16), coalesced float4 reads ----
    if constexpr (MODE == 3) {
#pragma unroll
        for (int i = 0; i < 16; i++) {
            int idx = i * 1024 + t * 4;          // element index, multiple of 4
            int row = idx >> 7, col = idx & 127;
            float4 v = *(const float4*)(Scp + (size_t)(m0 + row) * 128 + col);
            _Float16* d = sSc + row * 130 + col;
            d[0] = (_Float16)v.x; d[1] = (_Float16)v.y;
            d[2] = (_Float16)v.z; d[3] = (_Float16)v.w;
        }
    }

    auto STAGE = [&](int buf, int k) {
        gld16(A + aoff + k,           sAhi[buf] + ldsb);
        gld16(A + aoff + 16 * KD + k, sAhi[buf] + ldsb + 512);
        gld16(B + boff + k,           sBhi[buf] + ldsb);
        gld16(B + boff + 16 * KD + k, sBhi[buf] + ldsb + 512);
        if constexpr (SPLIT) {
            gld16(Alo + aoff + k,           sAlo + buf * 4096 + ldsb);
            gld16(Alo + aoff + 16 * KD + k, sAlo + buf * 4096 + ldsb + 512);
            gld16(Blo + boff + k,           sBlo + buf * 4096 + ldsb);
            gld16(Blo + boff + 16 * KD + k, sBlo + buf * 4096 + ldsb + 512);
        }
    };

    f32x4 acc[4][4] = {};

    // prologue: stage tile 0; __syncthreads drains vmcnt (staging) AND lgkm (Sc writes)
    STAGE(0, kbase);
    __syncthreads();

    for (int kt = 0; kt < NT; ++kt) {
        const int cur = kt & 1;
        const int k = kbase + kt * 32;

        // ---- fragment reads from buf cur ----
        bf16x8 ahi[4], alo[4], bhi[4], blo[4];
#pragma unroll
        for (int mt = 0; mt < 4; mt++) {
            ahi[mt] = *(const bf16x8*)(sAhi[cur] + offA[mt]);
            if constexpr (SPLIT) alo[mt] = *(const bf16x8*)(sAlo + cur * 4096 + offA[mt]);
        }
#pragma unroll
        for (int nt = 0; nt < 4; nt++) {
            bhi[nt] = *(const bf16x8*)(sBhi[cur] + offB[nt]);
            if constexpr (SPLIT) blo[nt] = *(const bf16x8*)(sBlo + cur * 4096 + offB[nt]);
        }
        if constexpr (MODE == 3) {
#pragma unroll
            for (int mt = 0; mt < 4; mt++) {
                _Float16 sc = sSc[(wr * 64 + mt * 16 + i16) * 130 + (k >> 6)];
                f16x8 av = __builtin_bit_cast(f16x8, ahi[mt]);
                av = av * sc;
                ahi[mt] = __builtin_bit_cast(bf16x8, av);
            }
        }

        // ---- issue next tile's staging (drained at tile end) ----
        if (kt + 1 < NT) STAGE(cur ^ 1, k + 32);

        // ---- MFMA ----
        __builtin_amdgcn_s_setprio(1);
#pragma unroll
        for (int nt = 0; nt < 4; nt++)
#pragma unroll
            for (int mt = 0; mt < 4; mt++) {
                if constexpr (MODE == 3) {
                    acc[mt][nt] = __builtin_amdgcn_mfma_f32_16x16x32_f16(
                        __builtin_bit_cast(f16x8, ahi[mt]), __builtin_bit_cast(f16x8, bhi[nt]),
                        acc[mt][nt], 0, 0, 0);
                } else {
                    acc[mt][nt] = __builtin_amdgcn_mfma_f32_16x16x32_bf16(ahi[mt], bhi[nt], acc[mt][nt], 0, 0, 0);
                    if constexpr (SPLIT) {
                        acc[mt][nt] = __builtin_amdgcn_mfma_f32_16x16x32_bf16(ahi[mt], blo[nt], acc[mt][nt], 0, 0, 0);
                        acc[mt][nt] = __builtin_amdgcn_mfma_f32_16x16x32_bf16(alo[mt], bhi[nt], acc[mt][nt], 0, 0, 0);
                    }
                }
            }
        __builtin_amdgcn_s_setprio(0);

        // ---- tile-end: drain next-tile staging, single barrier ----
        asm volatile("s_waitcnt vmcnt(0)" ::: "memory");
        __builtin_amdgcn_s_barrier();
        __builtin_amdgcn_sched_barrier(0);
    }

    // ---------------- epilogues ----------------
    if constexpr (MODE == 0) {
        // f16 hi/lo pair (2^-22 combined) for the 2-MFMA scores
#pragma unroll
        for (int mt = 0; mt < 4; mt++)
#pragma unroll
            for (int nt = 0; nt < 4; nt++)
#pragma unroll
                for (int r = 0; r < 4; r++) {
                    int row = m0 + wr * 64 + mt * 16 + quad * 4 + r;
                    int col = n0 + wc * 64 + nt * 16 + i16;
                    float v = acc[mt][nt][r];
                    _Float16 hv = (_Float16)v;
                    _Float16 lv = (_Float16)(v - (float)hv);
                    Chi[(size_t)row * DM + col] = __builtin_bit_cast(unsigned short, hv);
                    Clo[(size_t)row * DM + col] = __builtin_bit_cast(unsigned short, lv);
                }
    } else if constexpr (MODE == 1) {
        // transposed write: Vt[col][row], 4 consecutive rows per lane -> one 8B store
#pragma unroll
        for (int mt = 0; mt < 4; mt++)
#pragma unroll
            for (int nt = 0; nt < 4; nt++) {
                int row0 = m0 + wr * 64 + mt * 16 + quad * 4;
                int col  = n0 + wc * 64 + nt * 16 + i16;
                union { _Float16 h[4]; unsigned long long q; } p;
#pragma unroll
                for (int r = 0; r < 4; r++) p.h[r] = (_Float16)acc[mt][nt][r];
                *(unsigned long long*)(Cf16 + (size_t)col * SEQ + row0) = p.q;
            }
    } else if constexpr (MODE == 5) {
        // fp32 partial, transposed: Gp[z][e][d], one float4 store per fragment
        float* Gp = Cf32 + ((size_t)blockIdx.z << 20);
#pragma unroll
        for (int mt = 0; mt < 4; mt++)
#pragma unroll
            for (int nt = 0; nt < 4; nt++) {
                int row0 = m0 + wr * 64 + mt * 16 + quad * 4;
                int col  = n0 + wc * 64 + nt * 16 + i16;
                union { float f[4]; float4 v; } p;
#pragma unroll
                for (int r = 0; r < 4; r++) p.f[r] = acc[mt][nt][r];
                *(float4*)(Gp + (size_t)col * DM + row0) = p.v;
            }
    } else {  // MODE 3: PV, f32 out
#pragma unroll
        for (int mt = 0; mt < 4; mt++)
#pragma unroll
            for (int nt = 0; nt < 4; nt++)
#pragma unroll
                for (int r = 0; r < 4; r++) {
                    int row = m0 + wr * 64 + mt * 16 + quad * 4 + r;
                    int col = n0 + wc * 64 + nt * 16 + i16;
                    Cf32[(size_t)row * DM + col] = acc[mt][nt][r];
                }
    }
}

// ------- greduce: Ght[e][d] = split(sum_z Gp[z][e][d] - 256), coalesced -------
__global__ __launch_bounds__(256) void greduce(const float* __restrict__ Gp,
    unsigned short* __restrict__ Ghi, unsigned short* __restrict__ Glo)
{
    int e = blockIdx.x;
    int d0 = threadIdx.x * 4;
    float s[4] = {0.f, 0.f, 0.f, 0.f};
#pragma unroll
    for (int z = 0; z < 8; z++) {
        float4 v = *(const float4*)(Gp + ((size_t)z << 20) + (size_t)e * DM + d0);
        s[0] += v.x; s[1] += v.y; s[2] += v.z; s[3] += v.w;
    }
    unsigned short h[4], l[4];
#pragma unroll
    for (int j = 0; j < 4; j++) {
        float f = s[j] - 256.0f;
        h[j] = f2bf(f);
        l[j] = f2bf(f - bf2f(h[j]));
    }
    ushort4 hv = {h[0], h[1], h[2], h[3]};
    ushort4 lv = {l[0], l[1], l[2], l[3]};
    *(ushort4*)(Ghi + (size_t)e * DM + d0) = hv;
    *(ushort4*)(Glo + (size_t)e * DM + d0) = lv;
}

// ============ scores: 256x256 tile, 1024 thr (16 waves 4Mx4N of 64x64), BK=32 ============
// R14: 2-MFMA mixed-precision scores. A = y as f16 hi/lo pair (2^-22 combined, from
// MODE-0 epilogue), B = x as single f16 (2^-11). S = yh*x + yl*x: dropped cross terms
// are <= 2^-11 * |y*x| -> sigma(delta s) ~ 0.07 vs score gaps ~44 (R13 ablation showed
// M=3725cyc/tile is the serial floor; this cuts MFMA 48->32 and LDS streams 4->3).
// Schedule = R12 (verified): 1 barrier/K-tile, staging at tile top, drain at end.
// LDS 96KB (2buf x 3 streams). Swizzle R2-verified. XCD swizzle R3.
// G-trick epilogue: s = acc*scale + 8*rM*rN (exact rank-1 from fp32 row sums).
__global__ __launch_bounds__(1024) void scores256(
    const unsigned short* __restrict__ Yh, const unsigned short* __restrict__ Yl,
    const unsigned short* __restrict__ Xf,
    const float* __restrict__ rsum,
    _Float16* __restrict__ Eo, float* __restrict__ Tt, float* __restrict__ Zt)
{
    constexpr int KD = 1024;
    constexpr int NT = KD / 32;                       // 32 K-tiles
    // layout: buf(0/1) x {Yh,Yl,Xf} x [256][32]  = 96 KiB
    __shared__ alignas(16) unsigned short lds[2 * 3 * 8192];
    __shared__ float srM[256], srN[256];

    // bijective XCD swizzle (nwg=1024 % 8 == 0); m-major within an XCD
    const int flat = blockIdx.y * gridDim.x + blockIdx.x;
    const int wg = (flat & 7) * 128 + (flat >> 3);
    const int m0 = (wg >> 5) << 8;
    const int n0 = (wg & 31) << 8;

    const int t = threadIdx.x;
    const int wave = t >> 6, lane = t & 63;
    const int wr = wave >> 2, wc = wave & 3;          // 4x4 waves, 64x64 each
    const int i16 = lane & 15, quad = lane >> 4;

    // rank-1 row-sum slices -> LDS (visible by the prologue barrier)
    if (t < 256) srM[t] = rsum[m0 + t];
    else if (t < 512) srN[t - 256] = rsum[n0 + t - 256];

    // staging: 16 waves x 16 rows x 16B/lane covers one 256x32 stream per gld16
    const int srow = wave * 16 + (lane >> 2);
    const int scol = ((lane & 3) ^ ((lane >> 3) & 3)) << 3;
    const size_t ga = (size_t)(m0 + srow) * KD + scol;
    const size_t gb = (size_t)(n0 + srow) * KD + scol;
    const int ldw = wave * 512;                        // wave-uniform LDS el offset

    // fragment LDS element offsets (loop-invariant, swizzled)
    int offA[4], offB[4];
#pragma unroll
    for (int mt = 0; mt < 4; mt++) {
        int row = wr * 64 + mt * 16 + i16;
        offA[mt] = row * 32 + ((quad ^ ((row >> 1) & 3)) << 3);
    }
#pragma unroll
    for (int nt = 0; nt < 4; nt++) {
        int row = wc * 64 + nt * 16 + i16;
        offB[nt] = row * 32 + ((quad ^ ((row >> 1) & 3)) << 3);
    }

    f32x4 acc[4][4] = {};

    auto STAGE = [&](int buf, int kt) {
        unsigned short* p = lds + buf * 24576;
        const int k = kt * 32;
        gld16(Yh + ga + k, p + ldw);
        gld16(Yl + ga + k, p + 8192  + ldw);
        gld16(Xf + gb + k, p + 16384 + ldw);
    };

    // ---- prologue: stage tile 0 and DRAIN it (vmcnt, not lgkm!) before first reads ----
    STAGE(0, 0);
    asm volatile("s_waitcnt vmcnt(0)" ::: "memory");
    __builtin_amdgcn_s_barrier();
    __builtin_amdgcn_sched_barrier(0);

    for (int kt = 0; kt < NT; ++kt) {
        const int cur = kt & 1;
        const unsigned short* pAh = lds + cur * 24576;
        const unsigned short* pAl = pAh + 8192;
        const unsigned short* pBf = pAh + 16384;

        // ---- B fragments (4 reads, held); A streamed per row inside MFMA loop ----
        bf16x8 bf[4];
#pragma unroll
        for (int ni = 0; ni < 4; ni++)
            bf[ni] = *(const bf16x8*)(pBf + offB[ni]);
        // ---- issue next tile's staging (drained at tile end, ~full tile of cover) ----
        if (kt + 1 < NT) STAGE(cur ^ 1, kt + 1);

        __builtin_amdgcn_s_setprio(1);
#pragma unroll
        for (int mi = 0; mi < 4; mi++) {
            bf16x8 ah = *(const bf16x8*)(pAh + offA[mi]);
            bf16x8 al = *(const bf16x8*)(pAl + offA[mi]);
#pragma unroll
            for (int ni = 0; ni < 4; ni++) {
                f32x4 c = acc[mi][ni];
                c = __builtin_amdgcn_mfma_f32_16x16x32_f16(
                    __builtin_bit_cast(f16x8, ah), __builtin_bit_cast(f16x8, bf[ni]), c, 0, 0, 0);
                c = __builtin_amdgcn_mfma_f32_16x16x32_f16(
                    __builtin_bit_cast(f16x8, al), __builtin_bit_cast(f16x8, bf[ni]), c, 0, 0, 0);
                acc[mi][ni] = c;
            }
        }
        __builtin_amdgcn_s_setprio(0);

        // ---- tile-end: drain next-tile staging, single barrier ----
        asm volatile("s_waitcnt vmcnt(0)" ::: "memory");
        __builtin_amdgcn_s_barrier();
        __builtin_amdgcn_sched_barrier(0);
    }

    // ---- epilogue: s = acc*scale + 8*rM*rN; E = exp(s - tile64max), Tt, Zt ----
    const float scale = 0.03125f;  // 1/sqrt(1024)
    const float RC = 8.0f;         // 256 * scale
    const int tix = (n0 + wc * 64) >> 6;
    const float rn0 = RC * srN[wc * 64 + i16];
    const float rn1 = RC * srN[wc * 64 + 16 + i16];
    const float rn2 = RC * srN[wc * 64 + 32 + i16];
    const float rn3 = RC * srN[wc * 64 + 48 + i16];
#pragma unroll
    for (int mt = 0; mt < 4; mt++)
#pragma unroll
        for (int r = 0; r < 4; r++) {
            float rm = srM[wr * 64 + mt * 16 + quad * 4 + r];
            float s0 = acc[mt][0][r] * scale + rm * rn0;
            float s1 = acc[mt][1][r] * scale + rm * rn1;
            float s2 = acc[mt][2][r] * scale + rm * rn2;
            float s3 = acc[mt][3][r] * scale + rm * rn3;
            float mx = fmaxf(fmaxf(s0, s1), fmaxf(s2, s3));
            mx = fmaxf(mx, __shfl_xor(mx, 1));
            mx = fmaxf(mx, __shfl_xor(mx, 2));
            mx = fmaxf(mx, __shfl_xor(mx, 4));
            mx = fmaxf(mx, __shfl_xor(mx, 8));
            float e0 = __expf(s0 - mx), e1 = __expf(s1 - mx);
            float e2 = __expf(s2 - mx), e3 = __expf(s3 - mx);
            float z = e0 + e1 + e2 + e3;
            z += __shfl_xor(z, 1);
            z += __shfl_xor(z, 2);
            z += __shfl_xor(z, 4);
            z += __shfl_xor(z, 8);
            int row = m0 + wr * 64 + mt * 16 + quad * 4 + r;
            if (i16 == 0) {
                Tt[(size_t)row * 128 + tix] = mx;
                Zt[(size_t)row * 128 + tix] = z;
            }
            size_t eb = (size_t)row * SEQ + n0 + wc * 64 + i16;
            Eo[eb +  0] = (_Float16)e0;
            Eo[eb + 16] = (_Float16)e1;
            Eo[eb + 32] = (_Float16)e2;
            Eo[eb + 48] = (_Float16)e3;
        }
}

// ------- per-row softmax scale from per-tile stats: Sc[r][t] = e^{T-m}/l -------
__global__ __launch_bounds__(256) void sc_reduce(const float* __restrict__ Tt,
    const float* __restrict__ Zt, float* __restrict__ Sc)
{
    int row = blockIdx.x * 4 + (threadIdx.x >> 6);
    int lane = threadIdx.x & 63;
    size_t b = (size_t)row * 128 + lane;
    float t0 = Tt[b], t1 = Tt[b + 64];
    float z0 = Zt[b], z1 = Zt[b + 64];
    float m = fmaxf(t0, t1);
    for (int sh = 1; sh < 64; sh <<= 1) m = fmaxf(m, __shfl_xor(m, sh));
    float l = z0 * __expf(t0 - m) + z1 * __expf(t1 - m);
    for (int sh = 1; sh < 64; sh <<= 1) l += __shfl_xor(l, sh);
    float inv = 1.0f / l;
    Sc[b]      = __expf(t0 - m) * inv;
    Sc[b + 64] = __expf(t1 - m) * inv;
}

extern "C" void kernel_launch(void* const* d_in, const int* in_sizes, int n_in,
                              void* d_out, int out_size, void* d_ws, size_t ws_size,
                              hipStream_t stream)
{
    const float* x  = (const float*)d_in[0];
    const float* Wq = (const float*)d_in[1];
    const float* Wk = (const float*)d_in[2];
    const float* Wv = (const float*)d_in[3];
    float* Out = (float*)d_out;
    char* ws = (char*)d_ws;

    const size_t MB = 1024 * 1024;
    // Region [0,128MB): W splits + G buffers (all dead before scores) then E overwrites.
    unsigned short* Wqh  = (unsigned short*)(ws + 0 * MB);
    unsigned short* Wql  = (unsigned short*)(ws + 2 * MB);
    unsigned short* Wkh  = (unsigned short*)(ws + 4 * MB);
    unsigned short* Wkl  = (unsigned short*)(ws + 6 * MB);
    unsigned short* Wvth = (unsigned short*)(ws + 8 * MB);
    unsigned short* Wvtl = (unsigned short*)(ws + 10 * MB);
    unsigned short* Ghi  = (unsigned short*)(ws + 12 * MB);  // G't [e][d] split
    unsigned short* Glo  = (unsigned short*)(ws + 14 * MB);
    float*          Gp   = (float*)        (ws + 16 * MB);   // 8 x 4MB fp32 partials
    _Float16*       E    = (_Float16*)     (ws + 0 * MB);    // 128 MB

    size_t off = 128 * MB;
    unsigned short* Yhi = (unsigned short*)(ws + off); off += 16 * MB;  // f16 hi
    unsigned short* Ylo = (unsigned short*)(ws + off); off += 16 * MB;  // f16 lo
    unsigned short* xhi = (unsigned short*)(ws + off); off += 16 * MB;
    unsigned short* xlo = (unsigned short*)(ws + off); off += 16 * MB;
    _Float16*       xf  = (_Float16*)      (ws + off); off += 16 * MB;  // f16 single
    _Float16*       Vt  = (_Float16*)      (ws + off); off += 16 * MB;
    float*          Tt  = (float*)         (ws + off); off += (size_t)SEQ * 128 * 4;
    float*          Zt  = (float*)         (ws + off); off += (size_t)SEQ * 128 * 4;
    float*          Sc  = (float*)         (ws + off); off += (size_t)SEQ * 128 * 4;
    float*          rs  = (float*)         (ws + off); off += (size_t)SEQ * 4;

    // 1. split x (bf16 hi/lo + f16 single + row sums), split Wq/Wk, transpose+split Wv
    prep_kernel<<<8192 + 2048 + 256, 256, 0, stream>>>(x, xhi, xlo, xf, rs, Wq, Wk, Wv,
        Wqh, Wql, Wkh, Wkl, Wvth, Wvtl);
    // 2. G partials: split-K x8 (512 blocks, 4 K-tiles deep each)
    gemm128<5, DM><<<dim3(8, 8, 8), 256, 0, stream>>>(
        Wqh, Wql, Wkh, Wkl, nullptr, nullptr, nullptr, Gp, nullptr);
    // 2b. reduce partials -> G' = sum - 256, transposed split Ght[e][d]
    greduce<<<1024, 256, 0, stream>>>(Gp, Ghi, Glo);
    // 3. V projection, output written TRANSPOSED directly to Vt
    gemm128<1, DM><<<dim3(SEQ / 128, DM / 128), 256, 0, stream>>>(
        xhi, nullptr, Wvth, nullptr, nullptr, nullptr, (_Float16*)Vt, nullptr, nullptr);
    // 4. y' = x @ G' -> f16 hi/lo pair (replaces BOTH Q and K projections)
    gemm128<0, DM><<<dim3(SEQ / 128, DM / 128), 256, 0, stream>>>(
        xhi, xlo, Ghi, Glo, Yhi, Ylo, nullptr, nullptr, nullptr);
    // 5. scores: S = y' x^T * scale + 8 r r^T -> E, Tt, Zt   [2-MFMA f16 version]
    scores256<<<dim3(SEQ / 256, SEQ / 256), 1024, 0, stream>>>(
        Yhi, Ylo, (const unsigned short*)xf, rs, E, Tt, Zt);
    // 6. per-row/tile softmax scale
    sc_reduce<<<SEQ / 4, 256, 0, stream>>>(Tt, Zt, Sc);
    // 7. O = P @ V with P = E*Sc fused via LDS-staged Sc
    gemm128<3, SEQ><<<dim3(SEQ / 128, DM / 128), 256, 0, stream>>>(
        (const unsigned short*)E, nullptr, (const unsigned short*)Vt, nullptr,
        nullptr, nullptr, nullptr, Out, Sc);
}